// Round 3
// baseline (949.899 us; speedup 1.0000x reference)
//
#include <hip/hip_runtime.h>

#define BATCH 16384
#define XDIM  133
#define RPB   2

typedef __attribute__((ext_vector_type(4))) float f32x4;

__device__ __forceinline__ float relu(float v) { return fmaxf(v, 0.f); }

__global__ __launch_bounds__(256, 1)
void ac_fused(const float* __restrict__ x,
              const float* __restrict__ We,  const float* __restrict__ be,
              const float* __restrict__ Wh,  const float* __restrict__ bh,
              const float* __restrict__ Wa,  const float* __restrict__ ba,
              const float* __restrict__ W2,  const float* __restrict__ b2,
              const float* __restrict__ Wc1, const float* __restrict__ bc1,
              const float* __restrict__ Wc2, const float* __restrict__ bc2,
              const float* __restrict__ Wp1, const float* __restrict__ bp1,
              const float* __restrict__ Wp2, const float* __restrict__ bp2,
              const float* __restrict__ log_std,
              float* __restrict__ out)
{
    __shared__ __align__(16) float eS[RPB*64*128];   // 64 KB fp32, plain layout
    __shared__ __align__(16) float xs[RPB][136];
    __shared__            float attnS[RPB][64];
    __shared__ __align__(16) float mfS[RPB][128];
    __shared__ __align__(16) float tS[RPB][128];
    __shared__            float cpart[4][RPB];

    const int tid  = threadIdx.x;
    const int lane = tid & 63;
    const int wave = tid >> 6;
    const int b0   = blockIdx.x * RPB;

    // ---- phase 1: stage x rows ----
    for (int i = tid; i < RPB * XDIM; i += 256) {
        int r = i / XDIM;
        int c = i - r * XDIM;
        xs[r][c] = x[(size_t)b0 * XDIM + i];
    }
    __syncthreads();

    // ---- phase 2: e = relu(nb @ We^T + be) fp32 -> LDS; em.Wa_m partials ----
    {
        const int hp = lane;          // h pair (2hp, 2hp+1)
        const int q  = wave;          // n quarter
        const float w00 = We[hp*4+0], w01 = We[hp*4+1];
        const float w10 = We[hp*4+2], w11 = We[hp*4+3];
        const float be0 = be[hp*2],   be1 = be[hp*2+1];
        const float wam0 = Wa[128 + hp*2], wam1 = Wa[128 + hp*2+1];
        #pragma unroll
        for (int r = 0; r < RPB; ++r) {
            float ca = 0.f;
            #pragma unroll
            for (int i = 0; i < 16; ++i) {
                int n = q*16 + i;
                float nb0 = xs[r][5 + 2*n];
                float nb1 = xs[r][5 + 2*n + 1];
                float e0 = relu(fmaf(nb0, w00, fmaf(nb1, w01, be0)));
                float e1 = relu(fmaf(nb0, w10, fmaf(nb1, w11, be1)));
                ca = fmaf(e0, wam0, fmaf(e1, wam1, ca));
                float* dst = &eS[(r*64 + n)*128 + 2*hp];
                dst[0] = e0; dst[1] = e1;
            }
            #pragma unroll
            for (int off = 1; off < 64; off <<= 1) ca += __shfl_xor(ca, off);
            if (lane == 0) cpart[wave][r] = ca;
        }
    }
    __syncthreads();

    // ---- phase 3: score + softmax (exact fp32 e) ----
    if (wave < RPB) {
        const int r = wave;
        const int n = lane;
        const f32x4* erow = (const f32x4*)&eS[(r*64 + n)*128];
        const f32x4* wv   = (const f32x4*)Wa;
        float s = 0.f;
        #pragma unroll
        for (int k4 = 0; k4 < 32; ++k4) {
            f32x4 e = erow[k4], w = wv[k4];
            s = fmaf(e[0], w[0], s); s = fmaf(e[1], w[1], s);
            s = fmaf(e[2], w[2], s); s = fmaf(e[3], w[3], s);
        }
        float c = (cpart[0][r] + cpart[1][r] + cpart[2][r] + cpart[3][r]) * (1.f/64.f) + ba[0];
        float sc = relu(s + c);
        float m = sc;
        #pragma unroll
        for (int off = 1; off < 64; off <<= 1) m = fmaxf(m, __shfl_xor(m, off));
        float p = __expf(sc - m);
        float sum = p;
        #pragma unroll
        for (int off = 1; off < 64; off <<= 1) sum += __shfl_xor(sum, off);
        attnS[r][n] = p / (sum * 64.f);   // fold 1/64 of the mean
    }
    __syncthreads();

    // ---- phase 4: exact fp32 h-GEMM + attn pooling (one thread = one (r,o)) ----
    {
        const int o = tid & 127;
        const int r = tid >> 7;
        f32x4 whr[32];
        const f32x4* wrow = (const f32x4*)(Wh + o*128);
        #pragma unroll
        for (int k4 = 0; k4 < 32; ++k4) whr[k4] = wrow[k4];
        const float bho = bh[o];
        float acc = 0.f;
        for (int n = 0; n < 64; ++n) {
            const f32x4* erow = (const f32x4*)&eS[(r*64 + n)*128];
            float h = bho;
            #pragma unroll
            for (int k4 = 0; k4 < 32; ++k4) {
                f32x4 e = erow[k4], w = whr[k4];
                h = fmaf(e[0], w[0], h); h = fmaf(e[1], w[1], h);
                h = fmaf(e[2], w[2], h); h = fmaf(e[3], w[3], h);
            }
            acc = fmaf(attnS[r][n], relu(h), acc);
        }
        mfS[r][o] = acc;
    }
    __syncthreads();

    // ---- phase 5: t = relu(W2 @ [state5; mf] + b2) ----
    {
        const int o = tid & 127;
        const int r = tid >> 7;
        const float* w2row = W2 + o * XDIM;
        float s0 = b2[o];
        #pragma unroll
        for (int k = 0; k < 5; ++k) s0 = fmaf(w2row[k], xs[r][k], s0);
        #pragma unroll 8
        for (int k = 0; k < 128; ++k) s0 = fmaf(w2row[5+k], mfS[r][k], s0);
        tS[r][o] = relu(s0);
    }
    __syncthreads();

    // ---- phase 6: heads ----
    if (wave < RPB) {
        const int r = wave;
        float vp = 0.f, m0 = 0.f, m1 = 0.f;
        const f32x4* trow = (const f32x4*)&tS[r][0];
        #pragma unroll
        for (int oo = 0; oo < 4; ++oo) {
            int o = lane*4 + oo;
            const f32x4* c1row = (const f32x4*)(Wc1 + o*128);
            const f32x4* p1row = (const f32x4*)(Wp1 + o*128);
            float s1 = bc1[o], s2 = bp1[o];
            #pragma unroll 8
            for (int k4 = 0; k4 < 32; ++k4) {
                f32x4 w1 = c1row[k4], w2v = p1row[k4], tv = trow[k4];
                s1 = fmaf(w1[0], tv[0], s1); s1 = fmaf(w1[1], tv[1], s1);
                s1 = fmaf(w1[2], tv[2], s1); s1 = fmaf(w1[3], tv[3], s1);
                s2 = fmaf(w2v[0], tv[0], s2); s2 = fmaf(w2v[1], tv[1], s2);
                s2 = fmaf(w2v[2], tv[2], s2); s2 = fmaf(w2v[3], tv[3], s2);
            }
            float u  = relu(s1);
            float pp = relu(s2);
            vp = fmaf(Wc2[o],       u,  vp);
            m0 = fmaf(Wp2[o],       pp, m0);
            m1 = fmaf(Wp2[256 + o], pp, m1);
        }
        #pragma unroll
        for (int off = 1; off < 64; off <<= 1) {
            vp += __shfl_xor(vp, off);
            m0 += __shfl_xor(m0, off);
            m1 += __shfl_xor(m1, off);
        }
        if (lane == 0) {
            int b = b0 + r;
            out[b*2 + 0]           = m0 + bp2[0];
            out[b*2 + 1]           = m1 + bp2[1];
            out[2*BATCH + b*2 + 0] = expf(log_std[0]);
            out[2*BATCH + b*2 + 1] = expf(log_std[1]);
            out[4*BATCH + b]       = vp + bc2[0];
        }
    }
}

extern "C" void kernel_launch(void* const* d_in, const int* in_sizes, int n_in,
                              void* d_out, int out_size, void* d_ws, size_t ws_size,
                              hipStream_t stream) {
    (void)in_sizes; (void)n_in; (void)d_ws; (void)ws_size; (void)out_size;
    const float* x       = (const float*)d_in[0];
    const float* We      = (const float*)d_in[1];
    const float* be      = (const float*)d_in[2];
    const float* Wh      = (const float*)d_in[3];
    const float* bh      = (const float*)d_in[4];
    const float* Wa      = (const float*)d_in[5];
    const float* ba      = (const float*)d_in[6];
    const float* W2      = (const float*)d_in[7];
    const float* b2      = (const float*)d_in[8];
    const float* Wc1     = (const float*)d_in[9];
    const float* bc1     = (const float*)d_in[10];
    const float* Wc2     = (const float*)d_in[11];
    const float* bc2     = (const float*)d_in[12];
    const float* Wp1     = (const float*)d_in[13];
    const float* bp1     = (const float*)d_in[14];
    const float* Wp2     = (const float*)d_in[15];
    const float* bp2     = (const float*)d_in[16];
    const float* log_std = (const float*)d_in[17];

    dim3 grid(BATCH / RPB);
    dim3 block(256);
    hipLaunchKernelGGL(ac_fused, grid, block, 0, stream,
                       x, We, be, Wh, bh, Wa, ba, W2, b2,
                       Wc1, bc1, Wc2, bc2, Wp1, bp1, Wp2, bp2, log_std,
                       (float*)d_out);
}

// Round 4
// 217.126 us; speedup vs baseline: 4.3749x; 4.3749x over previous
//
#include <hip/hip_runtime.h>

#define BATCH 16384
#define XDIM  133
#define RPB   4     // batch rows per block
#define EROW  272   // bytes per e row: 136 halves (128 data + 4 pad) -> 16B-aligned

typedef __attribute__((ext_vector_type(8))) _Float16 half8;
typedef __attribute__((ext_vector_type(4))) float    f32x4;

__device__ __forceinline__ float relu(float v) { return fmaxf(v, 0.f); }

__device__ __forceinline__ unsigned short f2h(float f) {
    _Float16 h = (_Float16)f;                      // v_cvt_f16_f32
    return __builtin_bit_cast(unsigned short, h);
}

__global__ __launch_bounds__(256, 2)
void ac_fused(const float* __restrict__ x,
              const float* __restrict__ We,  const float* __restrict__ be,
              const float* __restrict__ Wh,  const float* __restrict__ bh,
              const float* __restrict__ Wa,  const float* __restrict__ ba,
              const float* __restrict__ W2,  const float* __restrict__ b2,
              const float* __restrict__ Wc1, const float* __restrict__ bc1,
              const float* __restrict__ Wc2, const float* __restrict__ bc2,
              const float* __restrict__ Wp1, const float* __restrict__ bp1,
              const float* __restrict__ Wp2, const float* __restrict__ bp2,
              const float* __restrict__ log_std,
              float* __restrict__ out)
{
    __shared__ __align__(16) char  eH[RPB * 64 * EROW];   // 68 KB fp16, plain padded
    __shared__ __align__(16) float xs[RPB][136];
    __shared__ __align__(16) float attnS[RPB][64];
    __shared__ __align__(16) float mfS[RPB][128];
    __shared__ __align__(16) float tS[RPB][128];
    __shared__            float cpart[4][RPB];
    __shared__            float redS[4][RPB][3];

    const int tid  = threadIdx.x;
    const int lane = tid & 63;
    const int wave = tid >> 6;
    const int b0   = blockIdx.x * RPB;

    // ---- phase 1: stage x rows ----
    for (int i = tid; i < RPB * XDIM; i += 256) {
        int r = i / XDIM;
        int c = i - r * XDIM;
        xs[r][c] = x[(size_t)b0 * XDIM + i];
    }
    __syncthreads();

    // ---- phase 2: e = relu(nb @ We^T + be) -> fp16 LDS (plain); em.Wa_m partials ----
    {
        const int hp = lane;          // h pair (2hp, 2hp+1)
        const int q  = wave;          // n quarter
        const float w00 = We[hp*4+0], w01 = We[hp*4+1];
        const float w10 = We[hp*4+2], w11 = We[hp*4+3];
        const float be0 = be[hp*2],   be1 = be[hp*2+1];
        const float wam0 = Wa[128 + hp*2], wam1 = Wa[128 + hp*2+1];
        #pragma unroll
        for (int r = 0; r < RPB; ++r) {
            float ca = 0.f;
            #pragma unroll
            for (int i = 0; i < 16; ++i) {
                int n = q*16 + i;
                float nb0 = xs[r][5 + 2*n];
                float nb1 = xs[r][5 + 2*n + 1];
                float e0 = relu(fmaf(nb0, w00, fmaf(nb1, w01, be0)));
                float e1 = relu(fmaf(nb0, w10, fmaf(nb1, w11, be1)));
                ca = fmaf(e0, wam0, fmaf(e1, wam1, ca));
                int row = r*64 + n;
                unsigned pk = (unsigned)f2h(e0) | ((unsigned)f2h(e1) << 16);
                *(unsigned*)(eH + row*EROW + (hp << 2)) = pk;
            }
            #pragma unroll
            for (int off = 1; off < 64; off <<= 1) ca += __shfl_xor(ca, off);
            if (lane == 0) cpart[wave][r] = ca;
        }
    }
    __syncthreads();

    // ---- phase 3: score + softmax (fp16 e, plain reads) ----
    {
        const int r = wave;
        const int n = lane;
        const int row = r*64 + n;
        float s = 0.f;
        #pragma unroll
        for (int k16 = 0; k16 < 16; ++k16) {
            half8 v = *(const half8*)(eH + row*EROW + k16*16);
            #pragma unroll
            for (int j = 0; j < 8; ++j)
                s = fmaf((float)v[j], Wa[k16*8 + j], s);
        }
        float c = (cpart[0][r] + cpart[1][r] + cpart[2][r] + cpart[3][r]) * (1.f/64.f) + ba[0];
        float sc = relu(s + c);
        float m = sc;
        #pragma unroll
        for (int off = 1; off < 64; off <<= 1) m = fmaxf(m, __shfl_xor(m, off));
        float p = __expf(sc - m);
        float sum = p;
        #pragma unroll
        for (int off = 1; off < 64; off <<= 1) sum += __shfl_xor(sum, off);
        attnS[r][n] = p / (sum * 64.f);   // fold 1/64 of the mean
    }
    __syncthreads();

    // ---- phase 4: h-GEMM via MFMA (fp16), fused attn-weighted pooling ----
    {
        const int c0 = wave*32 + (lane & 15);   // this wave owns cols [wave*32, +32)
        const int c1 = c0 + 16;
        const int g  = lane >> 4;               // k-group
        half8 bfr[2][4];
        #pragma unroll
        for (int kk = 0; kk < 4; ++kk) {
            int kb = kk*32 + g*8;
            const float* p0 = Wh + c0*128 + kb;
            const float* p1 = Wh + c1*128 + kb;
            f32x4 a0 = *(const f32x4*)p0;       f32x4 a1 = *(const f32x4*)(p0 + 4);
            f32x4 b0 = *(const f32x4*)p1;       f32x4 b1 = *(const f32x4*)(p1 + 4);
            half8 t0, t1;
            #pragma unroll
            for (int j = 0; j < 4; ++j) {
                t0[j]   = (_Float16)a0[j];  t0[4+j] = (_Float16)a1[j];
                t1[j]   = (_Float16)b0[j];  t1[4+j] = (_Float16)b1[j];
            }
            bfr[0][kk] = t0;  bfr[1][kk] = t1;
        }
        const float bh0 = bh[c0], bh1 = bh[c1];

        #pragma unroll
        for (int r = 0; r < RPB; ++r) {
            float mf0 = 0.f, mf1 = 0.f;
            #pragma unroll
            for (int nt = 0; nt < 4; ++nt) {
                const int arow = r*64 + nt*16 + (lane & 15);
                half8 af[4];
                #pragma unroll
                for (int kk = 0; kk < 4; ++kk)
                    af[kk] = *(const half8*)(eH + arow*EROW + kk*64 + g*16);
                f32x4 acc0 = {0.f, 0.f, 0.f, 0.f};
                f32x4 acc1 = {0.f, 0.f, 0.f, 0.f};
                #pragma unroll
                for (int kk = 0; kk < 4; ++kk) {
                    acc0 = __builtin_amdgcn_mfma_f32_16x16x32_f16(af[kk], bfr[0][kk], acc0, 0, 0, 0);
                    acc1 = __builtin_amdgcn_mfma_f32_16x16x32_f16(af[kk], bfr[1][kk], acc1, 0, 0, 0);
                }
                #pragma unroll
                for (int j = 0; j < 4; ++j) {
                    int n = nt*16 + g*4 + j;   // C/D: col=lane&15, row=(lane>>4)*4+j
                    float a = attnS[r][n];
                    mf0 = fmaf(a, relu(acc0[j] + bh0), mf0);
                    mf1 = fmaf(a, relu(acc1[j] + bh1), mf1);
                }
            }
            mf0 += __shfl_xor(mf0, 16);  mf0 += __shfl_xor(mf0, 32);
            mf1 += __shfl_xor(mf1, 16);  mf1 += __shfl_xor(mf1, 32);
            if (lane < 16) {
                mfS[r][wave*32 + lane]      = mf0;
                mfS[r][wave*32 + 16 + lane] = mf1;
            }
        }
    }
    __syncthreads();

    // ---- phase 5: t = relu(W2 @ [state5; mf] + b2) ----
    {
        const int o  = tid & 127;
        const int r0 = tid >> 7;         // 0 or 1
        const int r1 = r0 + 2;
        const float* w2row = W2 + o * XDIM;
        float s0 = b2[o], s1 = s0;
        #pragma unroll
        for (int k = 0; k < 5; ++k) {
            float w = w2row[k];
            s0 = fmaf(w, xs[r0][k], s0);
            s1 = fmaf(w, xs[r1][k], s1);
        }
        #pragma unroll 8
        for (int k = 0; k < 128; ++k) {
            float w = w2row[5 + k];
            s0 = fmaf(w, mfS[r0][k], s0);
            s1 = fmaf(w, mfS[r1][k], s1);
        }
        tS[r0][o] = relu(s0);
        tS[r1][o] = relu(s1);
    }
    __syncthreads();

    // ---- phase 6: heads — each thread owns ONE hidden unit o, all RPB rows ----
    {
        const int o = wave*64 + lane;    // 256 threads <-> 256 hidden units
        const f32x4* c1row = (const f32x4*)(Wc1 + o*128);
        const f32x4* p1row = (const f32x4*)(Wp1 + o*128);
        float s1[RPB], s2[RPB];
        const float bc1o = bc1[o], bp1o = bp1[o];
        #pragma unroll
        for (int r = 0; r < RPB; ++r) { s1[r] = bc1o; s2[r] = bp1o; }
        #pragma unroll 4
        for (int k4 = 0; k4 < 32; ++k4) {
            f32x4 w1 = c1row[k4];
            f32x4 w2v = p1row[k4];
            #pragma unroll
            for (int r = 0; r < RPB; ++r) {
                f32x4 tv = *(const f32x4*)&tS[r][k4*4];
                s1[r] = fmaf(w1[0], tv[0], s1[r]); s1[r] = fmaf(w1[1], tv[1], s1[r]);
                s1[r] = fmaf(w1[2], tv[2], s1[r]); s1[r] = fmaf(w1[3], tv[3], s1[r]);
                s2[r] = fmaf(w2v[0], tv[0], s2[r]); s2[r] = fmaf(w2v[1], tv[1], s2[r]);
                s2[r] = fmaf(w2v[2], tv[2], s2[r]); s2[r] = fmaf(w2v[3], tv[3], s2[r]);
            }
        }
        const float wc2 = Wc2[o], wp20 = Wp2[o], wp21 = Wp2[256 + o];
        float vp[RPB], m0[RPB], m1[RPB];
        #pragma unroll
        for (int r = 0; r < RPB; ++r) {
            float u  = relu(s1[r]);
            float pp = relu(s2[r]);
            vp[r] = wc2  * u;
            m0[r] = wp20 * pp;
            m1[r] = wp21 * pp;
        }
        #pragma unroll
        for (int off = 1; off < 64; off <<= 1) {
            #pragma unroll
            for (int r = 0; r < RPB; ++r) {
                vp[r] += __shfl_xor(vp[r], off);
                m0[r] += __shfl_xor(m0[r], off);
                m1[r] += __shfl_xor(m1[r], off);
            }
        }
        if (lane == 0) {
            #pragma unroll
            for (int r = 0; r < RPB; ++r) {
                redS[wave][r][0] = vp[r];
                redS[wave][r][1] = m0[r];
                redS[wave][r][2] = m1[r];
            }
        }
    }
    __syncthreads();

    if (tid < RPB) {
        const int r = tid;
        float V  = redS[0][r][0] + redS[1][r][0] + redS[2][r][0] + redS[3][r][0];
        float M0 = redS[0][r][1] + redS[1][r][1] + redS[2][r][1] + redS[3][r][1];
        float M1 = redS[0][r][2] + redS[1][r][2] + redS[2][r][2] + redS[3][r][2];
        int b = b0 + r;
        out[b*2 + 0]           = M0 + bp2[0];
        out[b*2 + 1]           = M1 + bp2[1];
        out[2*BATCH + b*2 + 0] = expf(log_std[0]);
        out[2*BATCH + b*2 + 1] = expf(log_std[1]);
        out[4*BATCH + b]       = V + bc2[0];
    }
}

extern "C" void kernel_launch(void* const* d_in, const int* in_sizes, int n_in,
                              void* d_out, int out_size, void* d_ws, size_t ws_size,
                              hipStream_t stream) {
    (void)in_sizes; (void)n_in; (void)d_ws; (void)ws_size; (void)out_size;
    const float* x       = (const float*)d_in[0];
    const float* We      = (const float*)d_in[1];
    const float* be      = (const float*)d_in[2];
    const float* Wh      = (const float*)d_in[3];
    const float* bh      = (const float*)d_in[4];
    const float* Wa      = (const float*)d_in[5];
    const float* ba      = (const float*)d_in[6];
    const float* W2      = (const float*)d_in[7];
    const float* b2      = (const float*)d_in[8];
    const float* Wc1     = (const float*)d_in[9];
    const float* bc1     = (const float*)d_in[10];
    const float* Wc2     = (const float*)d_in[11];
    const float* bc2     = (const float*)d_in[12];
    const float* Wp1     = (const float*)d_in[13];
    const float* bp1     = (const float*)d_in[14];
    const float* Wp2     = (const float*)d_in[15];
    const float* bp2     = (const float*)d_in[16];
    const float* log_std = (const float*)d_in[17];

    dim3 grid(BATCH / RPB);
    dim3 block(256);
    hipLaunchKernelGGL(ac_fused, grid, block, 0, stream,
                       x, We, be, Wh, bh, Wa, ba, W2, b2,
                       Wc1, bc1, Wc2, bc2, Wp1, bp1, Wp2, bp2, log_std,
                       (float*)d_out);
}

// Round 5
// 140.441 us; speedup vs baseline: 6.7637x; 1.5460x over previous
//
#include <hip/hip_runtime.h>

#define BATCH 16384
#define XDIM  133
#define RPB   2       // kernel A: batch rows per block
#define EROW  272     // A: e row pitch bytes (136 halves; 17x16B -> conflict-free)
#define MB    128     // kernel B: batch rows per block
#define CROW  336     // B: cat row pitch bytes (168 halves; 21x16B -> conflict-free)
#define TROW  272     // B: t row pitch bytes

typedef __attribute__((ext_vector_type(8))) _Float16 half8;
typedef __attribute__((ext_vector_type(4))) float    f32x4;
typedef __attribute__((ext_vector_type(4))) unsigned int uint4v;

__device__ __forceinline__ float relu(float v) { return fmaxf(v, 0.f); }

__device__ __forceinline__ unsigned short f2h(float f) {
    _Float16 h = (_Float16)f;
    return __builtin_bit_cast(unsigned short, h);
}

// ================= Kernel A: e -> softmax -> h-GEMM(MFMA) -> pooled mf =================
__global__ __launch_bounds__(256, 4)
void ac_attn(const float* __restrict__ x,
             const float* __restrict__ We,  const float* __restrict__ be,
             const float* __restrict__ Wh,  const float* __restrict__ bh,
             const float* __restrict__ Wa,  const float* __restrict__ ba,
             char* __restrict__ mfG)
{
    __shared__ __align__(16) char  eH[RPB * 64 * EROW];   // 34 KB fp16
    __shared__ __align__(16) float xs[RPB][136];
    __shared__ __align__(16) float attnS[RPB][64];
    __shared__ __align__(16) float mfS[RPB][128];
    __shared__            float cpart[4][RPB];

    const int tid  = threadIdx.x;
    const int lane = tid & 63;
    const int wave = tid >> 6;
    const int b0   = blockIdx.x * RPB;

    // ---- stage x rows ----
    for (int i = tid; i < RPB * XDIM; i += 256) {
        int r = i / XDIM;
        int c = i - r * XDIM;
        xs[r][c] = x[(size_t)b0 * XDIM + i];
    }
    __syncthreads();

    // ---- e = relu(nb @ We^T + be) -> fp16 LDS; em.Wa_m partials ----
    {
        const int hp = lane;
        const int q  = wave;
        const float w00 = We[hp*4+0], w01 = We[hp*4+1];
        const float w10 = We[hp*4+2], w11 = We[hp*4+3];
        const float be0 = be[hp*2],   be1 = be[hp*2+1];
        const float wam0 = Wa[128 + hp*2], wam1 = Wa[128 + hp*2+1];
        #pragma unroll
        for (int r = 0; r < RPB; ++r) {
            float ca = 0.f;
            #pragma unroll
            for (int i = 0; i < 16; ++i) {
                int n = q*16 + i;
                float nb0 = xs[r][5 + 2*n];
                float nb1 = xs[r][5 + 2*n + 1];
                float e0 = relu(fmaf(nb0, w00, fmaf(nb1, w01, be0)));
                float e1 = relu(fmaf(nb0, w10, fmaf(nb1, w11, be1)));
                ca = fmaf(e0, wam0, fmaf(e1, wam1, ca));
                int row = r*64 + n;
                unsigned pk = (unsigned)f2h(e0) | ((unsigned)f2h(e1) << 16);
                *(unsigned*)(eH + row*EROW + (hp << 2)) = pk;
            }
            #pragma unroll
            for (int off = 1; off < 64; off <<= 1) ca += __shfl_xor(ca, off);
            if (lane == 0) cpart[wave][r] = ca;
        }
    }
    __syncthreads();

    // ---- score + softmax ----
    if (wave < RPB) {
        const int r = wave;
        const int n = lane;
        const int row = r*64 + n;
        float s = 0.f;
        #pragma unroll
        for (int k16 = 0; k16 < 16; ++k16) {
            half8 v = *(const half8*)(eH + row*EROW + k16*16);
            #pragma unroll
            for (int j = 0; j < 8; ++j)
                s = fmaf((float)v[j], Wa[k16*8 + j], s);
        }
        float c = (cpart[0][r] + cpart[1][r] + cpart[2][r] + cpart[3][r]) * (1.f/64.f) + ba[0];
        float sc = relu(s + c);
        float m = sc;
        #pragma unroll
        for (int off = 1; off < 64; off <<= 1) m = fmaxf(m, __shfl_xor(m, off));
        float p = __expf(sc - m);
        float sum = p;
        #pragma unroll
        for (int off = 1; off < 64; off <<= 1) sum += __shfl_xor(sum, off);
        attnS[r][n] = p / (sum * 64.f);
    }
    __syncthreads();

    // ---- h-GEMM via MFMA + fused attn pooling ----
    {
        const int lo = lane & 15;
        const int g  = lane >> 4;
        const int c0 = wave*32 + lo;
        const int c1 = c0 + 16;
        half8 bfr[2][4];
        #pragma unroll
        for (int kk = 0; kk < 4; ++kk) {
            int kb = kk*32 + g*8;
            const float* p0 = Wh + c0*128 + kb;
            const float* p1 = Wh + c1*128 + kb;
            f32x4 a0 = *(const f32x4*)p0;       f32x4 a1 = *(const f32x4*)(p0 + 4);
            f32x4 b0 = *(const f32x4*)p1;       f32x4 b1 = *(const f32x4*)(p1 + 4);
            half8 t0, t1;
            #pragma unroll
            for (int j = 0; j < 4; ++j) {
                t0[j]   = (_Float16)a0[j];  t0[4+j] = (_Float16)a1[j];
                t1[j]   = (_Float16)b0[j];  t1[4+j] = (_Float16)b1[j];
            }
            bfr[0][kk] = t0;  bfr[1][kk] = t1;
        }
        const float bh0 = bh[c0], bh1 = bh[c1];

        #pragma unroll
        for (int r = 0; r < RPB; ++r) {
            float mf0 = 0.f, mf1 = 0.f;
            #pragma unroll
            for (int nt = 0; nt < 4; ++nt) {
                const int arow = r*64 + nt*16 + lo;
                half8 af[4];
                #pragma unroll
                for (int kk = 0; kk < 4; ++kk)
                    af[kk] = *(const half8*)(eH + arow*EROW + kk*64 + g*16);
                f32x4 acc0 = {0.f, 0.f, 0.f, 0.f};
                f32x4 acc1 = {0.f, 0.f, 0.f, 0.f};
                #pragma unroll
                for (int kk = 0; kk < 4; ++kk) {
                    acc0 = __builtin_amdgcn_mfma_f32_16x16x32_f16(af[kk], bfr[0][kk], acc0, 0, 0, 0);
                    acc1 = __builtin_amdgcn_mfma_f32_16x16x32_f16(af[kk], bfr[1][kk], acc1, 0, 0, 0);
                }
                f32x4 at4 = *(const f32x4*)&attnS[r][nt*16 + g*4];
                #pragma unroll
                for (int j = 0; j < 4; ++j) {
                    mf0 = fmaf(at4[j], relu(acc0[j] + bh0), mf0);
                    mf1 = fmaf(at4[j], relu(acc1[j] + bh1), mf1);
                }
            }
            mf0 += __shfl_xor(mf0, 16);  mf0 += __shfl_xor(mf0, 32);
            mf1 += __shfl_xor(mf1, 16);  mf1 += __shfl_xor(mf1, 32);
            if (lane < 16) {
                mfS[r][wave*32 + lane]      = mf0;
                mfS[r][wave*32 + 16 + lane] = mf1;
            }
        }
    }
    __syncthreads();

    // ---- write mf (fp16) to workspace ----
    if (tid < RPB * 64) {
        int r = tid >> 6, c = tid & 63;
        unsigned pk = (unsigned)f2h(mfS[r][2*c]) | ((unsigned)f2h(mfS[r][2*c+1]) << 16);
        *(unsigned*)(mfG + ((size_t)(b0 + r) * 128 + 2*c) * 2) = pk;
    }
}

// ================= Kernel B: t-GEMM + heads, M=128 rows/block, MFMA =================
__global__ __launch_bounds__(256, 2)
void ac_heads(const float* __restrict__ x, const char* __restrict__ mfG,
              const float* __restrict__ W2,  const float* __restrict__ b2,
              const float* __restrict__ Wc1, const float* __restrict__ bc1,
              const float* __restrict__ Wc2, const float* __restrict__ bc2,
              const float* __restrict__ Wp1, const float* __restrict__ bp1,
              const float* __restrict__ Wp2, const float* __restrict__ bp2,
              const float* __restrict__ log_std,
              float* __restrict__ out)
{
    __shared__ __align__(16) char catS[MB * CROW];   // 42 KB fp16: [mf(128) | state(5) | 0-pad]
    __shared__ __align__(16) char tS[MB * TROW];     // 34 KB fp16
    __shared__ float redV [2][MB];
    __shared__ float redM0[2][MB];
    __shared__ float redM1[2][MB];

    const int tid  = threadIdx.x;
    const int lane = tid & 63;
    const int wave = tid >> 6;
    const int lo   = lane & 15;
    const int g    = lane >> 4;
    const int b0   = blockIdx.x * MB;

    // ---- zero catS (pad region must be 0) ----
    for (int i = tid * 16; i < MB * CROW; i += 256 * 16)
        *(uint4v*)(catS + i) = (uint4v){0, 0, 0, 0};
    __syncthreads();

    // ---- fill cat: mf fp16 chunks + state5 ----
    for (int c = tid; c < MB * 16; c += 256) {
        int row = c >> 4, sl = c & 15;
        uint4v v = *(const uint4v*)(mfG + (size_t)(b0 + row) * 256 + sl * 16);
        *(uint4v*)(catS + row * CROW + sl * 16) = v;
    }
    for (int m = tid; m < MB; m += 256) {
        const float* xr = x + (size_t)(b0 + m) * XDIM;
        #pragma unroll
        for (int k = 0; k < 5; ++k)
            *(unsigned short*)(catS + m * CROW + 256 + 2*k) = f2h(xr[k]);
    }
    __syncthreads();

    // ---- t-GEMM: t = relu(cat @ W2eff^T + b2), K=160 (133 used) ----
    {
        half8 bf[2][5];
        const int o = wave * 32 + lo;         // wave owns cols [wave*32, +32)
        #pragma unroll
        for (int nt2 = 0; nt2 < 2; ++nt2) {
            const float* wrow = W2 + (size_t)(o + nt2*16) * XDIM;
            #pragma unroll
            for (int kk = 0; kk < 5; ++kk) {
                half8 t;
                #pragma unroll
                for (int j = 0; j < 8; ++j) {
                    int ck = kk*32 + g*8 + j;
                    float w;
                    if (ck < 128) w = wrow[5 + ck];
                    else { int sk = ck - 128; w = (sk < 5) ? wrow[sk] : 0.f; }
                    t[j] = (_Float16)w;
                }
                bf[nt2][kk] = t;
            }
        }
        const float bb0 = b2[o], bb1 = b2[o + 16];
        #pragma unroll
        for (int mt = 0; mt < 8; ++mt) {
            const int arow = mt*16 + lo;
            half8 af[5];
            #pragma unroll
            for (int kk = 0; kk < 5; ++kk)
                af[kk] = *(const half8*)(catS + arow*CROW + kk*64 + g*16);
            f32x4 a0 = {0.f,0.f,0.f,0.f}, a1 = {0.f,0.f,0.f,0.f};
            #pragma unroll
            for (int kk = 0; kk < 5; ++kk) {
                a0 = __builtin_amdgcn_mfma_f32_16x16x32_f16(af[kk], bf[0][kk], a0, 0, 0, 0);
                a1 = __builtin_amdgcn_mfma_f32_16x16x32_f16(af[kk], bf[1][kk], a1, 0, 0, 0);
            }
            #pragma unroll
            for (int j = 0; j < 4; ++j) {
                int m = mt*16 + g*4 + j;
                *(unsigned short*)(tS + m*TROW + o*2)        = f2h(relu(a0[j] + bb0));
                *(unsigned short*)(tS + m*TROW + (o+16)*2)   = f2h(relu(a1[j] + bb1));
            }
        }
    }
    __syncthreads();

    // ---- heads: waves 0,1 -> value (Wc1 o-range wave*128); waves 2,3 -> policy ----
    {
        const bool isval = (wave < 2);
        const float* W1 = isval ? Wc1 : Wp1;
        const float* bb = isval ? bc1 : bp1;
        const int obase = (wave & 1) * 128;
        float accA[8][4];   // value partial, or mu0 partial
        float accB[8][4];   // mu1 partial (policy only)
        #pragma unroll
        for (int mt = 0; mt < 8; ++mt)
            #pragma unroll
            for (int j = 0; j < 4; ++j) { accA[mt][j] = 0.f; accB[mt][j] = 0.f; }

        for (int np = 0; np < 4; ++np) {
            const int oA = obase + (np*2)*16 + lo;
            const int oB = oA + 16;
            half8 bf0[4], bf1[4];
            const float* wr0 = W1 + (size_t)oA * 128;
            const float* wr1 = W1 + (size_t)oB * 128;
            #pragma unroll
            for (int kk = 0; kk < 4; ++kk) {
                half8 t0, t1;
                #pragma unroll
                for (int j = 0; j < 8; ++j) {
                    t0[j] = (_Float16)wr0[kk*32 + g*8 + j];
                    t1[j] = (_Float16)wr1[kk*32 + g*8 + j];
                }
                bf0[kk] = t0; bf1[kk] = t1;
            }
            const float biasA = bb[oA], biasB = bb[oB];
            float c2A = 0.f, c2B = 0.f, p0A = 0.f, p0B = 0.f, p1A = 0.f, p1B = 0.f;
            if (isval) { c2A = Wc2[oA]; c2B = Wc2[oB]; }
            else       { p0A = Wp2[oA]; p0B = Wp2[oB]; p1A = Wp2[256+oA]; p1B = Wp2[256+oB]; }

            #pragma unroll
            for (int mt = 0; mt < 8; ++mt) {
                const int arow = mt*16 + lo;
                half8 af[4];
                #pragma unroll
                for (int kk = 0; kk < 4; ++kk)
                    af[kk] = *(const half8*)(tS + arow*TROW + kk*64 + g*16);
                f32x4 a0 = {0.f,0.f,0.f,0.f}, a1 = {0.f,0.f,0.f,0.f};
                #pragma unroll
                for (int kk = 0; kk < 4; ++kk) {
                    a0 = __builtin_amdgcn_mfma_f32_16x16x32_f16(af[kk], bf0[kk], a0, 0, 0, 0);
                    a1 = __builtin_amdgcn_mfma_f32_16x16x32_f16(af[kk], bf1[kk], a1, 0, 0, 0);
                }
                #pragma unroll
                for (int j = 0; j < 4; ++j) {
                    float uA = relu(a0[j] + biasA);
                    float uB = relu(a1[j] + biasB);
                    if (isval) {
                        float p = fmaf(c2A, uA, c2B * uB);
                        p += __shfl_xor(p, 1); p += __shfl_xor(p, 2);
                        p += __shfl_xor(p, 4); p += __shfl_xor(p, 8);
                        accA[mt][j] += p;
                    } else {
                        float q0 = fmaf(p0A, uA, p0B * uB);
                        float q1 = fmaf(p1A, uA, p1B * uB);
                        q0 += __shfl_xor(q0, 1); q0 += __shfl_xor(q0, 2);
                        q0 += __shfl_xor(q0, 4); q0 += __shfl_xor(q0, 8);
                        q1 += __shfl_xor(q1, 1); q1 += __shfl_xor(q1, 2);
                        q1 += __shfl_xor(q1, 4); q1 += __shfl_xor(q1, 8);
                        accA[mt][j] += q0;
                        accB[mt][j] += q1;
                    }
                }
            }
        }
        if (lo == 0) {
            #pragma unroll
            for (int mt = 0; mt < 8; ++mt)
                #pragma unroll
                for (int j = 0; j < 4; ++j) {
                    int m = mt*16 + g*4 + j;
                    if (isval) redV[wave][m] = accA[mt][j];
                    else { redM0[wave-2][m] = accA[mt][j]; redM1[wave-2][m] = accB[mt][j]; }
                }
        }
    }
    __syncthreads();

    // ---- final outputs ----
    {
        const float e0 = expf(log_std[0]), e1 = expf(log_std[1]);
        for (int m = tid; m < MB; m += 256) {
            int b = b0 + m;
            out[b*2 + 0]           = redM0[0][m] + redM0[1][m] + bp2[0];
            out[b*2 + 1]           = redM1[0][m] + redM1[1][m] + bp2[1];
            out[2*BATCH + b*2 + 0] = e0;
            out[2*BATCH + b*2 + 1] = e1;
            out[4*BATCH + b]       = redV[0][m] + redV[1][m] + bc2[0];
        }
    }
}

extern "C" void kernel_launch(void* const* d_in, const int* in_sizes, int n_in,
                              void* d_out, int out_size, void* d_ws, size_t ws_size,
                              hipStream_t stream) {
    (void)in_sizes; (void)n_in; (void)ws_size; (void)out_size;
    const float* x       = (const float*)d_in[0];
    const float* We      = (const float*)d_in[1];
    const float* be      = (const float*)d_in[2];
    const float* Wh      = (const float*)d_in[3];
    const float* bh      = (const float*)d_in[4];
    const float* Wa      = (const float*)d_in[5];
    const float* ba      = (const float*)d_in[6];
    const float* W2      = (const float*)d_in[7];
    const float* b2      = (const float*)d_in[8];
    const float* Wc1     = (const float*)d_in[9];
    const float* bc1     = (const float*)d_in[10];
    const float* Wc2     = (const float*)d_in[11];
    const float* bc2     = (const float*)d_in[12];
    const float* Wp1     = (const float*)d_in[13];
    const float* bp1     = (const float*)d_in[14];
    const float* Wp2     = (const float*)d_in[15];
    const float* bp2     = (const float*)d_in[16];
    const float* log_std = (const float*)d_in[17];
    char* mfG = (char*)d_ws;                 // BATCH*128 fp16 = 4 MB

    hipLaunchKernelGGL(ac_attn, dim3(BATCH / RPB), dim3(256), 0, stream,
                       x, We, be, Wh, bh, Wa, ba, mfG);
    hipLaunchKernelGGL(ac_heads, dim3(BATCH / MB), dim3(256), 0, stream,
                       x, mfG, W2, b2, Wc1, bc1, Wc2, bc2, Wp1, bp1, Wp2, bp2,
                       log_std, (float*)d_out);
}

// Round 7
// 81.156 us; speedup vs baseline: 11.7046x; 1.7305x over previous
//
#include <hip/hip_runtime.h>

#define BATCH 16384
#define XDIM  133
#define RPB   2       // kernel A: batch rows per block
#define EROW  272     // A: e row pitch bytes (136 halves; 16B-aligned rows)
#define MB    64      // kernel B: batch rows per block
#define CROW  336     // B: cat row pitch bytes (168 halves)
#define TROW  272     // B: t row pitch bytes

// d_ws layout (halves unless noted)
#define WH_OFF   0        // Wh16   [128][128]   16384 halves
#define W2_OFF   16384    // W2e16  [128][160]   20480 halves (K padded 133->160, reordered [mf|state|0])
#define WC1_OFF  36864    // Wc1_16 [256][128]   32768 halves
#define WP1_OFF  69632    // Wp1_16 [256][128]   32768 halves
#define WA_OFF   102400   // Wa_e16 [128]          128 halves
#define MFG_OFF  208896   // byte offset: mf fp16 [BATCH][128] = 4 MB

typedef __attribute__((ext_vector_type(8))) _Float16 half8;
typedef __attribute__((ext_vector_type(2))) _Float16 half2v;
typedef __attribute__((ext_vector_type(4))) float    f32x4;
typedef __attribute__((ext_vector_type(4))) unsigned int uint4v;

__device__ __forceinline__ float relu(float v) { return fmaxf(v, 0.f); }
__device__ __forceinline__ unsigned short f2h(float f) {
    _Float16 h = (_Float16)f;
    return __builtin_bit_cast(unsigned short, h);
}
__device__ __forceinline__ half2v pk2h(float a, float b) {
    return __builtin_bit_cast(half2v, __builtin_amdgcn_cvt_pkrtz(a, b));
}

// ================= Kernel P: weight fp16 prep =================
__global__ __launch_bounds__(256)
void ac_prep(const float* __restrict__ Wh, const float* __restrict__ W2,
             const float* __restrict__ Wc1, const float* __restrict__ Wp1,
             const float* __restrict__ Wa, unsigned short* __restrict__ wsH)
{
    const int idx = blockIdx.x * 256 + threadIdx.x;
    const int stride = gridDim.x * 256;
    for (int i = idx; i < 128*128; i += stride) wsH[WH_OFF + i] = f2h(Wh[i]);
    for (int i = idx; i < 128*160; i += stride) {
        int o = i / 160, ck = i - o*160;
        float w = (ck < 128) ? W2[o*XDIM + 5 + ck]
                             : ((ck < 133) ? W2[o*XDIM + (ck - 128)] : 0.f);
        wsH[W2_OFF + i] = f2h(w);
    }
    for (int i = idx; i < 256*128; i += stride) wsH[WC1_OFF + i] = f2h(Wc1[i]);
    for (int i = idx; i < 256*128; i += stride) wsH[WP1_OFF + i] = f2h(Wp1[i]);
    for (int i = idx; i < 128;     i += stride) wsH[WA_OFF  + i] = f2h(Wa[i]);
}

// ================= Kernel A: e -> softmax -> h-GEMM(MFMA) -> pooled mf =================
__global__ __launch_bounds__(256, 4)
void ac_attn(const float* __restrict__ x,
             const float* __restrict__ We,  const float* __restrict__ be,
             const float* __restrict__ bh,
             const float* __restrict__ Wa,  const float* __restrict__ ba,
             const unsigned short* __restrict__ wsH,
             char* __restrict__ mfG)
{
    __shared__ __align__(16) char  eH[RPB * 64 * EROW];   // 34 KB fp16
    __shared__ __align__(16) float xs[RPB][128];          // nb only, pair-aligned
    __shared__ __align__(16) float attnS[RPB][64];
    __shared__ __align__(16) float mfS[RPB][128];
    __shared__ __align__(16) float pS[4][64];
    __shared__            float cpart[4][RPB];

    const int tid  = threadIdx.x;
    const int lane = tid & 63;
    const int wave = tid >> 6;
    const int b0   = blockIdx.x * RPB;

    // ---- stage nb (x cols 5..132) ----
    {
        int r = tid >> 7, c = tid & 127;
        xs[r][c] = x[(size_t)(b0 + r) * XDIM + 5 + c];
    }
    __syncthreads();

    // ---- e = relu(nb @ We^T + be) -> fp16 LDS; em.Wa_m partials ----
    {
        const int hp = lane;
        const int q  = wave;
        const float w00 = We[hp*4+0], w01 = We[hp*4+1];
        const float w10 = We[hp*4+2], w11 = We[hp*4+3];
        const float be0 = be[hp*2],   be1 = be[hp*2+1];
        const float wam0 = Wa[128 + hp*2], wam1 = Wa[128 + hp*2+1];
        #pragma unroll
        for (int r = 0; r < RPB; ++r) {
            float ca = 0.f;
            #pragma unroll
            for (int i = 0; i < 16; ++i) {
                int n = q*16 + i;
                float2 nb = *(const float2*)&xs[r][2*n];
                float e0 = relu(fmaf(nb.x, w00, fmaf(nb.y, w01, be0)));
                float e1 = relu(fmaf(nb.x, w10, fmaf(nb.y, w11, be1)));
                ca = fmaf(e0, wam0, fmaf(e1, wam1, ca));
                int row = r*64 + n;
                *(half2v*)(eH + row*EROW + (hp << 2)) = pk2h(e0, e1);
            }
            #pragma unroll
            for (int off = 1; off < 64; off <<= 1) ca += __shfl_xor(ca, off);
            if (lane == 0) cpart[wave][r] = ca;
        }
    }
    __syncthreads();

    // ---- score partials: wave (r = w&1, khalf = w>>1), fdot2 ----
    {
        const int r  = wave & 1;
        const int kh = wave >> 1;
        const int n  = lane;
        const int row = r*64 + n;
        const half2v* wa = (const half2v*)(wsH + WA_OFF) + kh*32;
        float s = 0.f;
        #pragma unroll
        for (int k16 = 0; k16 < 8; ++k16) {
            half8 v = *(const half8*)(eH + row*EROW + kh*128 + k16*16);
            const half2v* v2 = (const half2v*)&v;
            #pragma unroll
            for (int j = 0; j < 4; ++j)
                s = __builtin_amdgcn_fdot2(v2[j], wa[k16*4 + j], s, false);
        }
        pS[wave][n] = s;
    }
    __syncthreads();

    // ---- softmax (waves 0..RPB-1) ----
    if (wave < RPB) {
        const int r = wave;
        const int n = lane;
        float s = pS[r][n] + pS[2 + r][n];
        float c = (cpart[0][r] + cpart[1][r] + cpart[2][r] + cpart[3][r]) * (1.f/64.f) + ba[0];
        float sc = relu(s + c);
        float m = sc;
        #pragma unroll
        for (int off = 1; off < 64; off <<= 1) m = fmaxf(m, __shfl_xor(m, off));
        float p = __expf(sc - m);
        float sum = p;
        #pragma unroll
        for (int off = 1; off < 64; off <<= 1) sum += __shfl_xor(sum, off);
        attnS[r][n] = p / (sum * 64.f);
    }
    __syncthreads();

    // ---- h-GEMM via MFMA (fp16 weights preconverted) + fused attn pooling ----
    {
        const int lo = lane & 15;
        const int g  = lane >> 4;
        const int c0 = wave*32 + lo;
        const int c1 = c0 + 16;
        const unsigned short* WhH = wsH + WH_OFF;
        half8 bfr[2][4];
        #pragma unroll
        for (int kk = 0; kk < 4; ++kk) {
            int kb = kk*32 + g*8;
            bfr[0][kk] = *(const half8*)(WhH + c0*128 + kb);
            bfr[1][kk] = *(const half8*)(WhH + c1*128 + kb);
        }
        const float bh0 = bh[c0], bh1 = bh[c1];

        #pragma unroll
        for (int r = 0; r < RPB; ++r) {
            float mf0 = 0.f, mf1 = 0.f;
            #pragma unroll
            for (int nt = 0; nt < 4; ++nt) {
                const int arow = r*64 + nt*16 + lo;
                half8 af[4];
                #pragma unroll
                for (int kk = 0; kk < 4; ++kk)
                    af[kk] = *(const half8*)(eH + arow*EROW + kk*64 + g*16);
                f32x4 acc0 = {0.f, 0.f, 0.f, 0.f};
                f32x4 acc1 = {0.f, 0.f, 0.f, 0.f};
                #pragma unroll
                for (int kk = 0; kk < 4; ++kk) {
                    acc0 = __builtin_amdgcn_mfma_f32_16x16x32_f16(af[kk], bfr[0][kk], acc0, 0, 0, 0);
                    acc1 = __builtin_amdgcn_mfma_f32_16x16x32_f16(af[kk], bfr[1][kk], acc1, 0, 0, 0);
                }
                f32x4 at4 = *(const f32x4*)&attnS[r][nt*16 + g*4];
                #pragma unroll
                for (int j = 0; j < 4; ++j) {
                    mf0 = fmaf(at4[j], relu(acc0[j] + bh0), mf0);
                    mf1 = fmaf(at4[j], relu(acc1[j] + bh1), mf1);
                }
            }
            mf0 += __shfl_xor(mf0, 16);  mf0 += __shfl_xor(mf0, 32);
            mf1 += __shfl_xor(mf1, 16);  mf1 += __shfl_xor(mf1, 32);
            if (lane < 16) {
                mfS[r][wave*32 + lane]      = mf0;
                mfS[r][wave*32 + 16 + lane] = mf1;
            }
        }
    }
    __syncthreads();

    // ---- write mf (fp16) to workspace ----
    if (tid < RPB * 64) {
        int r = tid >> 6, c = tid & 63;
        *(half2v*)(mfG + ((size_t)(b0 + r) * 128 + 2*c) * 2) = pk2h(mfS[r][2*c], mfS[r][2*c+1]);
    }
}

// ================= Kernel B: t-GEMM + heads, MB=64 rows/block =================
__global__ __launch_bounds__(256, 1)
void ac_heads(const float* __restrict__ x, const char* __restrict__ mfG,
              const unsigned short* __restrict__ wsH,
              const float* __restrict__ b2,
              const float* __restrict__ bc1, const float* __restrict__ Wc2,
              const float* __restrict__ bc2,
              const float* __restrict__ bp1, const float* __restrict__ Wp2,
              const float* __restrict__ bp2,
              const float* __restrict__ log_std,
              float* __restrict__ out)
{
    __shared__ __align__(16) char catS[MB * CROW];   // 21 KB
    __shared__ __align__(16) char tS[MB * TROW];     // 17 KB
    __shared__ float redV [2][MB];
    __shared__ float redM0[2][MB];
    __shared__ float redM1[2][MB];

    const int tid  = threadIdx.x;
    const int lane = tid & 63;
    const int wave = tid >> 6;
    const int lo   = lane & 15;
    const int g    = lane >> 4;
    const int b0   = blockIdx.x * MB;

    // ---- zero catS then fill [mf(128) | state(5) | 0-pad to 160] ----
    for (int i = tid * 16; i < MB * CROW; i += 256 * 16)
        *(uint4v*)(catS + i) = (uint4v){0, 0, 0, 0};
    __syncthreads();
    for (int c = tid; c < MB * 16; c += 256) {
        int row = c >> 4, sl = c & 15;
        uint4v v = *(const uint4v*)(mfG + (size_t)(b0 + row) * 256 + sl * 16);
        *(uint4v*)(catS + row * CROW + sl * 16) = v;
    }
    for (int m = tid; m < MB; m += 256) {
        const float* xr = x + (size_t)(b0 + m) * XDIM;
        #pragma unroll
        for (int k = 0; k < 5; ++k)
            *(unsigned short*)(catS + m * CROW + 256 + 2*k) = f2h(xr[k]);
    }
    __syncthreads();

    // ---- t-GEMM: t = relu(cat @ W2eff^T + b2), K=160 ----
    {
        const int o = wave * 32 + lo;
        const unsigned short* W2H = wsH + W2_OFF;
        half8 bw[2][5];
        #pragma unroll
        for (int nt2 = 0; nt2 < 2; ++nt2)
            #pragma unroll
            for (int kk = 0; kk < 5; ++kk)
                bw[nt2][kk] = *(const half8*)(W2H + (size_t)(o + nt2*16)*160 + kk*32 + g*8);
        const float bb0 = b2[o], bb1 = b2[o + 16];
        #pragma unroll
        for (int mt = 0; mt < 4; ++mt) {
            const int arow = mt*16 + lo;
            half8 af[5];
            #pragma unroll
            for (int kk = 0; kk < 5; ++kk)
                af[kk] = *(const half8*)(catS + arow*CROW + kk*64 + g*16);
            f32x4 a0 = {0.f,0.f,0.f,0.f}, a1 = {0.f,0.f,0.f,0.f};
            #pragma unroll
            for (int kk = 0; kk < 5; ++kk) {
                a0 = __builtin_amdgcn_mfma_f32_16x16x32_f16(af[kk], bw[0][kk], a0, 0, 0, 0);
                a1 = __builtin_amdgcn_mfma_f32_16x16x32_f16(af[kk], bw[1][kk], a1, 0, 0, 0);
            }
            #pragma unroll
            for (int j = 0; j < 4; ++j) {
                int m = mt*16 + g*4 + j;
                *(unsigned short*)(tS + m*TROW + o*2)      = f2h(relu(a0[j] + bb0));
                *(unsigned short*)(tS + m*TROW + (o+16)*2) = f2h(relu(a1[j] + bb1));
            }
        }
    }
    __syncthreads();

    // ---- heads: waves 0,1 -> value; waves 2,3 -> policy; per-lane acc, reduce once ----
    {
        const bool isval = (wave < 2);
        const unsigned short* W1H = wsH + (isval ? WC1_OFF : WP1_OFF);
        const float* bb = isval ? bc1 : bp1;
        const int obase = (wave & 1) * 128;
        float sA[4][4], sB[4][4];
        #pragma unroll
        for (int mt = 0; mt < 4; ++mt)
            #pragma unroll
            for (int j = 0; j < 4; ++j) { sA[mt][j] = 0.f; sB[mt][j] = 0.f; }

        #pragma unroll
        for (int np = 0; np < 4; ++np) {
            const int oA = obase + np*32 + lo;
            const int oB = oA + 16;
            half8 bf0[4], bf1[4];
            #pragma unroll
            for (int kk = 0; kk < 4; ++kk) {
                bf0[kk] = *(const half8*)(W1H + (size_t)oA*128 + kk*32 + g*8);
                bf1[kk] = *(const half8*)(W1H + (size_t)oB*128 + kk*32 + g*8);
            }
            const float biasA = bb[oA], biasB = bb[oB];
            float wA0, wB0, wA1 = 0.f, wB1 = 0.f;
            if (isval) { wA0 = Wc2[oA]; wB0 = Wc2[oB]; }
            else       { wA0 = Wp2[oA]; wB0 = Wp2[oB]; wA1 = Wp2[256+oA]; wB1 = Wp2[256+oB]; }

            #pragma unroll
            for (int mt = 0; mt < 4; ++mt) {
                const int arow = mt*16 + lo;
                half8 af[4];
                #pragma unroll
                for (int kk = 0; kk < 4; ++kk)
                    af[kk] = *(const half8*)(tS + arow*TROW + kk*64 + g*16);
                f32x4 a0 = {0.f,0.f,0.f,0.f}, a1 = {0.f,0.f,0.f,0.f};
                #pragma unroll
                for (int kk = 0; kk < 4; ++kk) {
                    a0 = __builtin_amdgcn_mfma_f32_16x16x32_f16(af[kk], bf0[kk], a0, 0, 0, 0);
                    a1 = __builtin_amdgcn_mfma_f32_16x16x32_f16(af[kk], bf1[kk], a1, 0, 0, 0);
                }
                #pragma unroll
                for (int j = 0; j < 4; ++j) {
                    float uA = relu(a0[j] + biasA);
                    float uB = relu(a1[j] + biasB);
                    sA[mt][j] += wA0*uA + wB0*uB;
                    sB[mt][j] += wA1*uA + wB1*uB;
                }
            }
        }
        #pragma unroll
        for (int mt = 0; mt < 4; ++mt)
            #pragma unroll
            for (int j = 0; j < 4; ++j) {
                #pragma unroll
                for (int off = 1; off < 16; off <<= 1) {
                    sA[mt][j] += __shfl_xor(sA[mt][j], off);
                    sB[mt][j] += __shfl_xor(sB[mt][j], off);
                }
            }
        if (lo == 0) {
            #pragma unroll
            for (int mt = 0; mt < 4; ++mt)
                #pragma unroll
                for (int j = 0; j < 4; ++j) {
                    int m = mt*16 + g*4 + j;
                    if (isval) redV[wave][m] = sA[mt][j];
                    else { redM0[wave-2][m] = sA[mt][j]; redM1[wave-2][m] = sB[mt][j]; }
                }
        }
    }
    __syncthreads();

    // ---- final outputs ----
    if (tid < MB) {
        const int m = tid;
        const int b = b0 + m;
        out[b*2 + 0]           = redM0[0][m] + redM0[1][m] + bp2[0];
        out[b*2 + 1]           = redM1[0][m] + redM1[1][m] + bp2[1];
        out[2*BATCH + b*2 + 0] = expf(log_std[0]);
        out[2*BATCH + b*2 + 1] = expf(log_std[1]);
        out[4*BATCH + b]       = redV[0][m] + redV[1][m] + bc2[0];
    }
}

extern "C" void kernel_launch(void* const* d_in, const int* in_sizes, int n_in,
                              void* d_out, int out_size, void* d_ws, size_t ws_size,
                              hipStream_t stream) {
    (void)in_sizes; (void)n_in; (void)ws_size; (void)out_size;
    const float* x       = (const float*)d_in[0];
    const float* We      = (const float*)d_in[1];
    const float* be      = (const float*)d_in[2];
    const float* Wh      = (const float*)d_in[3];
    const float* bh      = (const float*)d_in[4];
    const float* Wa      = (const float*)d_in[5];
    const float* ba      = (const float*)d_in[6];
    const float* W2      = (const float*)d_in[7];
    const float* b2      = (const float*)d_in[8];
    const float* Wc1     = (const float*)d_in[9];
    const float* bc1     = (const float*)d_in[10];
    const float* Wc2     = (const float*)d_in[11];
    const float* bc2     = (const float*)d_in[12];
    const float* Wp1     = (const float*)d_in[13];
    const float* bp1     = (const float*)d_in[14];
    const float* Wp2     = (const float*)d_in[15];
    const float* bp2     = (const float*)d_in[16];
    const float* log_std = (const float*)d_in[17];

    unsigned short* wsH = (unsigned short*)d_ws;
    char* mfG = (char*)d_ws + MFG_OFF;

    hipLaunchKernelGGL(ac_prep, dim3(64), dim3(256), 0, stream,
                       Wh, W2, Wc1, Wp1, Wa, wsH);
    hipLaunchKernelGGL(ac_attn, dim3(BATCH / RPB), dim3(256), 0, stream,
                       x, We, be, bh, Wa, ba, wsH, mfG);
    hipLaunchKernelGGL(ac_heads, dim3(BATCH / MB), dim3(256), 0, stream,
                       x, mfG, wsH, b2, bc1, Wc2, bc2, bp1, Wp2, bp2,
                       log_std, (float*)d_out);
}